// Round 5
// baseline (906.839 us; speedup 1.0000x reference)
//
#include <hip/hip_runtime.h>
#include <hip/hip_bf16.h>

#define NN 131072      // nodes
#define EE 2097152     // edges
#define NG 256         // graphs
#define TT 8
#define NB 512         // dst buckets (256 nodes each)
#define BCAP 5120      // bucket capacity (mean 4096, +16 sigma)
#define MAXW 32        // ELL width (overflow -> exact ovf list)
#define OVFCAP 16384

// ---------- zero (int) ----------
__global__ __launch_bounds__(256) void k_zero_i(int* __restrict__ p, int n) {
  int i = blockIdx.x * 256 + threadIdx.x;
  if (i < n) p[i] = 0;
}

// ---------- pass 1: partition edges into dst buckets, packed (dlow<<17)|src ----------
__global__ __launch_bounds__(256) void k_part(const int* __restrict__ ei, int* __restrict__ bcur,
                                              int* __restrict__ pairs) {
  int e = blockIdx.x * 256 + threadIdx.x;
  if (e >= EE) return;
  int s = ei[e], d = ei[EE + e];
  int b = d >> 8;
  int k = atomicAdd(&bcur[b], 1);
  if (k < BCAP) __builtin_nontemporal_store(((d & 255) << 17) | s, &pairs[(size_t)b * BCAP + k]);
}

// ---------- pass 2: per-bucket ELL build in LDS, dense writeout ----------
__global__ __launch_bounds__(256) void k_bucket(const int* __restrict__ pairs, const int* __restrict__ bcur,
                                                int* __restrict__ col, int* __restrict__ cnt,
                                                int* __restrict__ ovfcnt, int2* __restrict__ ovf) {
  __shared__ int lcnt[256];
  __shared__ int lell[256 * MAXW];
  int b = blockIdx.x, tid = threadIdx.x;
  lcnt[tid] = 0;
  __syncthreads();
  int m = min(bcur[b], BCAP);
  const int* pb = pairs + (size_t)b * BCAP;
  for (int i = tid; i < m; i += 256) {
    int p = pb[i];
    int s = p & 0x1FFFF, dl = p >> 17;
    int k = atomicAdd(&lcnt[dl], 1);
    if (k < MAXW) lell[dl * MAXW + k] = s;
    else {
      int oi = atomicAdd(ovfcnt, 1);
      if (oi < OVFCAP) ovf[oi] = make_int2(b * 256 + dl, s);
    }
  }
  __syncthreads();
  int4* dst4 = (int4*)(col + (size_t)b * 256 * MAXW);
  const int4* src4 = (const int4*)lell;
#pragma unroll
  for (int i = 0; i < (256 * MAXW / 4) / 256; ++i)
    dst4[tid + i * 256] = src4[tid + i * 256];
  cnt[b * 256 + tid] = lcnt[tid];
}

// ---------- GEMM: Y[n,c] = sum_k X'[n,k] * W[k,c], X' = relu(X + bias_in) if relu_bias ----------
__global__ __launch_bounds__(256) void k_gemm(const float* __restrict__ X, const float* __restrict__ W,
                                              const float* __restrict__ bias_in, int relu_bias,
                                              float* __restrict__ Y) {
  __shared__ float xs[64 * 64];
  __shared__ float ws[64 * 64];
  int tid = threadIdx.x;
  size_t row0 = (size_t)blockIdx.x * 64;
#pragma unroll
  for (int i = 0; i < 16; ++i) ws[tid + i * 256] = W[tid + i * 256];
#pragma unroll
  for (int i = 0; i < 4; ++i) {
    int idx = tid + i * 256;
    int r = idx >> 4, q = idx & 15;
    float4 v = ((const float4*)(X + (row0 + r) * 64))[q];
    if (relu_bias) {
      int c0 = q * 4;
      v.x = fmaxf(v.x + bias_in[c0 + 0], 0.f);
      v.y = fmaxf(v.y + bias_in[c0 + 1], 0.f);
      v.z = fmaxf(v.z + bias_in[c0 + 2], 0.f);
      v.w = fmaxf(v.w + bias_in[c0 + 3], 0.f);
    }
    *(float4*)&xs[idx * 4] = v;
  }
  __syncthreads();
  int c = tid & 63, rg = tid >> 6;
  float acc[16];
#pragma unroll
  for (int i = 0; i < 16; ++i) acc[i] = 0.f;
#pragma unroll 4
  for (int kq = 0; kq < 16; ++kq) {
    float w0 = ws[(kq * 4 + 0) * 64 + c];
    float w1 = ws[(kq * 4 + 1) * 64 + c];
    float w2 = ws[(kq * 4 + 2) * 64 + c];
    float w3 = ws[(kq * 4 + 3) * 64 + c];
#pragma unroll
    for (int i = 0; i < 16; ++i) {
      const float4 xv = *(const float4*)&xs[(rg + i * 4) * 64 + kq * 4];
      acc[i] += xv.x * w0 + xv.y * w1 + xv.z * w2 + xv.w * w3;
    }
  }
#pragma unroll
  for (int i = 0; i < 16; ++i)
    Y[(row0 + rg + (size_t)i * 4) * 64 + c] = acc[i];
}

// ---------- ELL gather: one wave per dst node, lane = feature ----------
__global__ __launch_bounds__(256) void k_gather_ell(const float* __restrict__ H, const int* __restrict__ cnt,
                                                    const int* __restrict__ col, float* __restrict__ agg) {
  int lane = threadIdx.x & 63;
  int node = blockIdx.x * 4 + (threadIdx.x >> 6);
  int deg = cnt[node];
  float dn = rsqrtf((float)deg + 1.0f);
  float acc = H[(size_t)node * 64 + lane] * (dn * dn);   // self loop
  int m = min(deg, MAXW);
  const int* crow = col + (size_t)node * MAXW;
  int myc = (lane < m) ? crow[lane] : 0;
  float mydinv = (lane < m) ? rsqrtf((float)cnt[myc] + 1.0f) : 0.f;
  int j = 0;
  for (; j + 4 <= m; j += 4) {
    int s0 = __shfl(myc, j),     s1 = __shfl(myc, j + 1);
    int s2 = __shfl(myc, j + 2), s3 = __shfl(myc, j + 3);
    float c0 = __shfl(mydinv, j),     c1 = __shfl(mydinv, j + 1);
    float c2 = __shfl(mydinv, j + 2), c3 = __shfl(mydinv, j + 3);
    float h0 = H[(size_t)s0 * 64 + lane];
    float h1 = H[(size_t)s1 * 64 + lane];
    float h2 = H[(size_t)s2 * 64 + lane];
    float h3 = H[(size_t)s3 * 64 + lane];
    acc += h0 * (c0 * dn) + h1 * (c1 * dn) + h2 * (c2 * dn) + h3 * (c3 * dn);
  }
  for (; j < m; ++j) {
    int s0 = __shfl(myc, j);
    float c0 = __shfl(mydinv, j);
    acc += H[(size_t)s0 * 64 + lane] * (c0 * dn);
  }
  agg[(size_t)node * 64 + lane] = acc;
}

// ---------- exact overflow fix-up (deg > MAXW edges), ~20 entries ----------
__global__ __launch_bounds__(64) void k_ovf(const int2* __restrict__ ovf, const int* __restrict__ ovfcnt,
                                            const int* __restrict__ cnt, const float* __restrict__ H,
                                            float* __restrict__ agg) {
  int lane = threadIdx.x;
  int n = min(*ovfcnt, OVFCAP);
  for (int i = blockIdx.x; i < n; i += gridDim.x) {
    int d = ovf[i].x, s = ovf[i].y;
    float v = H[(size_t)s * 64 + lane] * rsqrtf((float)cnt[s] + 1.0f) * rsqrtf((float)cnt[d] + 1.0f);
    atomicAdd(&agg[(size_t)d * 64 + lane], v);
  }
}

// ---------- node blur ----------
__global__ __launch_bounds__(256) void k_blur(const float* __restrict__ agg2, const float* __restrict__ b2,
                                              float* __restrict__ z) {
  int idx = blockIdx.x * 256 + threadIdx.x;
  if (idx >= NG * TT * 64) return;
  int f = idx & 63, t = (idx >> 6) & 7, g = idx >> 9;
  const float* base = agg2 + ((size_t)g * 512 + (size_t)t) * 64 + f;
  float acc = 0.f;
#pragma unroll
  for (int rr = 0; rr < 64; ++rr) {
    float w = (float)(63 - rr) * (1.0f / 63.0f);
    acc += w * base[(size_t)rr * 8 * 64];
  }
  z[idx] = acc + 32.0f * b2[f];
}

// ---------- classifier head ----------
__global__ __launch_bounds__(64) void k_head(const float* __restrict__ z,
    const float* __restrict__ w1, const float* __restrict__ b1,
    const float* __restrict__ w2, const float* __restrict__ b2,
    const float* __restrict__ w3, const float* __restrict__ b3,
    float* __restrict__ out) {
  __shared__ float zs[512];
  __shared__ float r[64];
  int g = blockIdx.x, c = threadIdx.x;
#pragma unroll
  for (int i = 0; i < 8; ++i) zs[c + i * 64] = z[(size_t)g * 512 + c + i * 64];
  __syncthreads();
  float a = b1[c];
  for (int j = 0; j < 512; ++j) a += zs[j] * w1[j * 64 + c];
  float mem = 0.f, rate = 0.f;
#pragma unroll
  for (int s = 0; s < 4; ++s) {
    float reset = (mem > 1.0f) ? 1.0f : 0.0f;
    mem = 0.9f * mem + a - reset;
    if (mem - 1.0f > 0.0f) rate += 1.0f;
  }
  r[c] = rate * 0.25f;
  __syncthreads();
  float a2 = b2[c];
#pragma unroll
  for (int j = 0; j < 64; ++j) a2 += r[j] * w2[j * 64 + c];
  __syncthreads();
  mem = 0.f; rate = 0.f;
#pragma unroll
  for (int s = 0; s < 4; ++s) {
    float reset = (mem > 1.0f) ? 1.0f : 0.0f;
    mem = 0.9f * mem + a2 - reset;
    if (mem - 1.0f > 0.0f) rate += 1.0f;
  }
  r[c] = rate * 0.25f;
  __syncthreads();
  if (c < 10) {
    float o = b3[c];
#pragma unroll
    for (int j = 0; j < 64; ++j) o += r[j] * w3[j * 10 + c];
    out[(size_t)g * 10 + c] = o;
  }
}

extern "C" void kernel_launch(void* const* d_in, const int* in_sizes, int n_in,
                              void* d_out, int out_size, void* d_ws, size_t ws_size,
                              hipStream_t stream) {
  const float* x   = (const float*)d_in[0];
  const int*   ei  = (const int*)d_in[1];
  const float* c1w = (const float*)d_in[3];
  const float* c1b = (const float*)d_in[4];
  const float* c2w = (const float*)d_in[5];
  const float* c2b = (const float*)d_in[6];
  const float* l1w = (const float*)d_in[7];
  const float* l1b = (const float*)d_in[8];
  const float* l2w = (const float*)d_in[9];
  const float* l2b = (const float*)d_in[10];
  const float* l3w = (const float*)d_in[11];
  const float* l3b = (const float*)d_in[12];
  float* out = (float*)d_out;

  char* w = (char*)d_ws;
  size_t off = 0;
  float* bufA = (float*)(w + off); off += (size_t)NN * 64 * 4;   // 32 MB (pairs overlay)
  float* bufB = (float*)(w + off); off += (size_t)NN * 64 * 4;   // 32 MB
  int* col    = (int*)(w + off);   off += (size_t)NN * MAXW * 4; // 16 MB
  int* cnt    = (int*)(w + off);   off += (size_t)NN * 4;        // 0.5 MB
  float* z    = (float*)(w + off); off += (size_t)NG * TT * 64 * 4;
  int* meta   = (int*)(w + off);   off += (NB + 16) * 4;         // bcur[512] + ovfcnt
  int2* ovf   = (int2*)(w + off);  off += (size_t)OVFCAP * 8;
  int* bcur   = meta;
  int* ovfcnt = meta + NB;
  int* pairs  = (int*)bufA;        // dead until k_gemm (after k_bucket) - safe overlay

  // graph build: partition -> per-bucket LDS ELL
  k_zero_i<<<3, 256, 0, stream>>>(meta, NB + 1);
  k_part<<<EE / 256, 256, 0, stream>>>(ei, bcur, pairs);
  k_bucket<<<NB, 256, 0, stream>>>(pairs, bcur, col, cnt, ovfcnt, ovf);

  // layer 1
  k_gemm<<<NN / 64, 256, 0, stream>>>(x, c1w, nullptr, 0, bufA);
  k_gather_ell<<<NN / 4, 256, 0, stream>>>(bufA, cnt, col, bufB);
  k_ovf<<<32, 64, 0, stream>>>(ovf, ovfcnt, cnt, bufA, bufB);

  // layer 2
  k_gemm<<<NN / 64, 256, 0, stream>>>(bufB, c2w, c1b, 1, bufA);
  k_gather_ell<<<NN / 4, 256, 0, stream>>>(bufA, cnt, col, bufB);
  k_ovf<<<32, 64, 0, stream>>>(ovf, ovfcnt, cnt, bufA, bufB);

  // blur + head
  k_blur<<<NG * TT * 64 / 256, 256, 0, stream>>>(bufB, c2b, z);
  k_head<<<NG, 64, 0, stream>>>(z, l1w, l1b, l2w, l2b, l3w, l3b, out);
}

// Round 6
// 373.652 us; speedup vs baseline: 2.4270x; 2.4270x over previous
//
#include <hip/hip_runtime.h>
#include <hip/hip_bf16.h>

#define NN 131072      // nodes
#define EE 2097152     // edges
#define NG 256         // graphs
#define TT 8
#define NB 512         // dst buckets (256 nodes each)
#define NBLK 256       // partition blocks (8192 edges each)
#define SCAP 64        // per-(block,bucket) segment capacity (Poisson(16), P(>64)~1e-20)
#define MAXW 32        // ELL width (overflow -> exact ovfB list)
#define OVFA_CAP 4096
#define OVFB_CAP 16384

// ---------- zero (int) ----------
__global__ __launch_bounds__(256) void k_zero_i(int* __restrict__ p, int n) {
  int i = blockIdx.x * 256 + threadIdx.x;
  if (i < n) p[i] = 0;
}

// ---------- pass 1: block-private partition, LDS cursors (no global atomics) ----------
__global__ __launch_bounds__(256) void k_part2(const int* __restrict__ ei, int* __restrict__ pairs,
                                               int* __restrict__ cnt2, int* __restrict__ ovfAcnt,
                                               int2* __restrict__ ovfA) {
  __shared__ int lcur[NB];
  int tid = threadIdx.x, blk = blockIdx.x;
  lcur[tid] = 0; lcur[tid + 256] = 0;
  __syncthreads();
  int e0 = blk * (EE / NBLK);
#pragma unroll 4
  for (int i = 0; i < (EE / NBLK) / 256; ++i) {
    int e = e0 + i * 256 + tid;
    int s = ei[e], d = ei[EE + e];
    int b = d >> 8;
    int k = atomicAdd(&lcur[b], 1);
    if (k < SCAP)
      __builtin_nontemporal_store(((d & 255) << 17) | s,
                                  &pairs[((size_t)b * NBLK + blk) * SCAP + k]);
    else {
      int oi = atomicAdd(ovfAcnt, 1);
      if (oi < OVFA_CAP) ovfA[oi] = make_int2(d, s);
    }
  }
  __syncthreads();
  cnt2[(size_t)tid * NBLK + blk] = min(lcur[tid], SCAP);
  cnt2[(size_t)(tid + 256) * NBLK + blk] = min(lcur[tid + 256], SCAP);
}

// ---------- pass 2: per-bucket ELL build in LDS, coalesced segment reads ----------
__global__ __launch_bounds__(256) void k_bucket(const int* __restrict__ pairs, const int* __restrict__ cnt2,
                                                int* __restrict__ col, int* __restrict__ cnt,
                                                const int* __restrict__ ovfAcnt, const int2* __restrict__ ovfA,
                                                int* __restrict__ ovfBcnt, int2* __restrict__ ovfB) {
  __shared__ int lcnt[256];
  __shared__ int lell[256 * MAXW];
  __shared__ int scnt[NBLK];
  int b = blockIdx.x, tid = threadIdx.x;
  lcnt[tid] = 0;
  scnt[tid] = cnt2[(size_t)b * NBLK + tid];
  __syncthreads();
  const int* pb = pairs + (size_t)b * NBLK * SCAP;
  for (int idx = tid; idx < NBLK * SCAP; idx += 256) {
    int blk = idx / SCAP, slot = idx % SCAP;
    if (slot < scnt[blk]) {
      int p = pb[idx];
      int s = p & 0x1FFFF, dl = p >> 17;
      int k = atomicAdd(&lcnt[dl], 1);
      if (k < MAXW) lell[dl * MAXW + k] = s;
      else {
        int oi = atomicAdd(ovfBcnt, 1);
        if (oi < OVFB_CAP) ovfB[oi] = make_int2(b * 256 + dl, s);
      }
    }
  }
  // segment-overflow edges (expected zero)
  int na = min(*ovfAcnt, OVFA_CAP);
  for (int i = tid; i < na; i += 256) {
    int d = ovfA[i].x, s = ovfA[i].y;
    if ((d >> 8) == b) {
      int dl = d & 255;
      int k = atomicAdd(&lcnt[dl], 1);
      if (k < MAXW) lell[dl * MAXW + k] = s;
      else {
        int oi = atomicAdd(ovfBcnt, 1);
        if (oi < OVFB_CAP) ovfB[oi] = make_int2(d, s);
      }
    }
  }
  __syncthreads();
  int4* dst4 = (int4*)(col + (size_t)b * 256 * MAXW);
  const int4* src4 = (const int4*)lell;
#pragma unroll
  for (int i = 0; i < (256 * MAXW / 4) / 256; ++i)
    dst4[tid + i * 256] = src4[tid + i * 256];
  cnt[b * 256 + tid] = lcnt[tid];
}

// ---------- GEMM: Y[n,c] = sum_k X'[n,k] * W[k,c], X' = relu(X + bias_in) if relu_bias ----------
__global__ __launch_bounds__(256) void k_gemm(const float* __restrict__ X, const float* __restrict__ W,
                                              const float* __restrict__ bias_in, int relu_bias,
                                              float* __restrict__ Y) {
  __shared__ float xs[64 * 64];
  __shared__ float ws[64 * 64];
  int tid = threadIdx.x;
  size_t row0 = (size_t)blockIdx.x * 64;
#pragma unroll
  for (int i = 0; i < 16; ++i) ws[tid + i * 256] = W[tid + i * 256];
#pragma unroll
  for (int i = 0; i < 4; ++i) {
    int idx = tid + i * 256;
    int r = idx >> 4, q = idx & 15;
    float4 v = ((const float4*)(X + (row0 + r) * 64))[q];
    if (relu_bias) {
      int c0 = q * 4;
      v.x = fmaxf(v.x + bias_in[c0 + 0], 0.f);
      v.y = fmaxf(v.y + bias_in[c0 + 1], 0.f);
      v.z = fmaxf(v.z + bias_in[c0 + 2], 0.f);
      v.w = fmaxf(v.w + bias_in[c0 + 3], 0.f);
    }
    *(float4*)&xs[idx * 4] = v;
  }
  __syncthreads();
  int c = tid & 63, rg = tid >> 6;
  float acc[16];
#pragma unroll
  for (int i = 0; i < 16; ++i) acc[i] = 0.f;
#pragma unroll 4
  for (int kq = 0; kq < 16; ++kq) {
    float w0 = ws[(kq * 4 + 0) * 64 + c];
    float w1 = ws[(kq * 4 + 1) * 64 + c];
    float w2 = ws[(kq * 4 + 2) * 64 + c];
    float w3 = ws[(kq * 4 + 3) * 64 + c];
#pragma unroll
    for (int i = 0; i < 16; ++i) {
      const float4 xv = *(const float4*)&xs[(rg + i * 4) * 64 + kq * 4];
      acc[i] += xv.x * w0 + xv.y * w1 + xv.z * w2 + xv.w * w3;
    }
  }
#pragma unroll
  for (int i = 0; i < 16; ++i)
    Y[(row0 + rg + (size_t)i * 4) * 64 + c] = acc[i];
}

// ---------- ELL gather: one wave per dst node, lane = feature ----------
__global__ __launch_bounds__(256) void k_gather_ell(const float* __restrict__ H, const int* __restrict__ cnt,
                                                    const int* __restrict__ col, float* __restrict__ agg) {
  int lane = threadIdx.x & 63;
  int node = blockIdx.x * 4 + (threadIdx.x >> 6);
  int deg = cnt[node];
  float dn = rsqrtf((float)deg + 1.0f);
  float acc = H[(size_t)node * 64 + lane] * (dn * dn);   // self loop
  int m = min(deg, MAXW);
  const int* crow = col + (size_t)node * MAXW;
  int myc = (lane < m) ? crow[lane] : 0;
  float mydinv = (lane < m) ? rsqrtf((float)cnt[myc] + 1.0f) : 0.f;
  int j = 0;
  for (; j + 4 <= m; j += 4) {
    int s0 = __shfl(myc, j),     s1 = __shfl(myc, j + 1);
    int s2 = __shfl(myc, j + 2), s3 = __shfl(myc, j + 3);
    float c0 = __shfl(mydinv, j),     c1 = __shfl(mydinv, j + 1);
    float c2 = __shfl(mydinv, j + 2), c3 = __shfl(mydinv, j + 3);
    float h0 = H[(size_t)s0 * 64 + lane];
    float h1 = H[(size_t)s1 * 64 + lane];
    float h2 = H[(size_t)s2 * 64 + lane];
    float h3 = H[(size_t)s3 * 64 + lane];
    acc += h0 * (c0 * dn) + h1 * (c1 * dn) + h2 * (c2 * dn) + h3 * (c3 * dn);
  }
  for (; j < m; ++j) {
    int s0 = __shfl(myc, j);
    float c0 = __shfl(mydinv, j);
    acc += H[(size_t)s0 * 64 + lane] * (c0 * dn);
  }
  agg[(size_t)node * 64 + lane] = acc;
}

// ---------- exact ELL-overflow fix-up (deg > MAXW edges), ~handful ----------
__global__ __launch_bounds__(64) void k_ovf(const int2* __restrict__ ovf, const int* __restrict__ ovfcnt,
                                            const int* __restrict__ cnt, const float* __restrict__ H,
                                            float* __restrict__ agg) {
  int lane = threadIdx.x;
  int n = min(*ovfcnt, OVFB_CAP);
  for (int i = blockIdx.x; i < n; i += gridDim.x) {
    int d = ovf[i].x, s = ovf[i].y;
    float v = H[(size_t)s * 64 + lane] * rsqrtf((float)cnt[s] + 1.0f) * rsqrtf((float)cnt[d] + 1.0f);
    atomicAdd(&agg[(size_t)d * 64 + lane], v);
  }
}

// ---------- node blur ----------
__global__ __launch_bounds__(256) void k_blur(const float* __restrict__ agg2, const float* __restrict__ b2,
                                              float* __restrict__ z) {
  int idx = blockIdx.x * 256 + threadIdx.x;
  if (idx >= NG * TT * 64) return;
  int f = idx & 63, t = (idx >> 6) & 7, g = idx >> 9;
  const float* base = agg2 + ((size_t)g * 512 + (size_t)t) * 64 + f;
  float acc = 0.f;
#pragma unroll
  for (int rr = 0; rr < 64; ++rr) {
    float w = (float)(63 - rr) * (1.0f / 63.0f);
    acc += w * base[(size_t)rr * 8 * 64];
  }
  z[idx] = acc + 32.0f * b2[f];
}

// ---------- classifier head ----------
__global__ __launch_bounds__(64) void k_head(const float* __restrict__ z,
    const float* __restrict__ w1, const float* __restrict__ b1,
    const float* __restrict__ w2, const float* __restrict__ b2,
    const float* __restrict__ w3, const float* __restrict__ b3,
    float* __restrict__ out) {
  __shared__ float zs[512];
  __shared__ float r[64];
  int g = blockIdx.x, c = threadIdx.x;
#pragma unroll
  for (int i = 0; i < 8; ++i) zs[c + i * 64] = z[(size_t)g * 512 + c + i * 64];
  __syncthreads();
  float a = b1[c];
  for (int j = 0; j < 512; ++j) a += zs[j] * w1[j * 64 + c];
  float mem = 0.f, rate = 0.f;
#pragma unroll
  for (int s = 0; s < 4; ++s) {
    float reset = (mem > 1.0f) ? 1.0f : 0.0f;
    mem = 0.9f * mem + a - reset;
    if (mem - 1.0f > 0.0f) rate += 1.0f;
  }
  r[c] = rate * 0.25f;
  __syncthreads();
  float a2 = b2[c];
#pragma unroll
  for (int j = 0; j < 64; ++j) a2 += r[j] * w2[j * 64 + c];
  __syncthreads();
  mem = 0.f; rate = 0.f;
#pragma unroll
  for (int s = 0; s < 4; ++s) {
    float reset = (mem > 1.0f) ? 1.0f : 0.0f;
    mem = 0.9f * mem + a2 - reset;
    if (mem - 1.0f > 0.0f) rate += 1.0f;
  }
  r[c] = rate * 0.25f;
  __syncthreads();
  if (c < 10) {
    float o = b3[c];
#pragma unroll
    for (int j = 0; j < 64; ++j) o += r[j] * w3[j * 10 + c];
    out[(size_t)g * 10 + c] = o;
  }
}

extern "C" void kernel_launch(void* const* d_in, const int* in_sizes, int n_in,
                              void* d_out, int out_size, void* d_ws, size_t ws_size,
                              hipStream_t stream) {
  const float* x   = (const float*)d_in[0];
  const int*   ei  = (const int*)d_in[1];
  const float* c1w = (const float*)d_in[3];
  const float* c1b = (const float*)d_in[4];
  const float* c2w = (const float*)d_in[5];
  const float* c2b = (const float*)d_in[6];
  const float* l1w = (const float*)d_in[7];
  const float* l1b = (const float*)d_in[8];
  const float* l2w = (const float*)d_in[9];
  const float* l2b = (const float*)d_in[10];
  const float* l3w = (const float*)d_in[11];
  const float* l3b = (const float*)d_in[12];
  float* out = (float*)d_out;

  char* w = (char*)d_ws;
  size_t off = 0;
  float* bufA = (float*)(w + off); off += (size_t)NN * 64 * 4;     // 33.5 MB (pairs overlay)
  float* bufB = (float*)(w + off); off += (size_t)NN * 64 * 4;     // 33.5 MB
  int* col    = (int*)(w + off);   off += (size_t)NN * MAXW * 4;   // 16.8 MB
  int* cnt    = (int*)(w + off);   off += (size_t)NN * 4;          // 0.5 MB
  int* cnt2   = (int*)(w + off);   off += (size_t)NB * NBLK * 4;   // 0.5 MB
  float* z    = (float*)(w + off); off += (size_t)NG * TT * 64 * 4;
  int* meta   = (int*)(w + off);   off += 16 * 4;                  // ovfAcnt, ovfBcnt
  int2* ovfA  = (int2*)(w + off);  off += (size_t)OVFA_CAP * 8;
  int2* ovfB  = (int2*)(w + off);  off += (size_t)OVFB_CAP * 8;
  int* ovfAcnt = meta;
  int* ovfBcnt = meta + 1;
  int* pairs   = (int*)bufA;       // 512*256*64*4 = 33.5 MB, dead before GEMM1

  // graph build: block-private partition -> per-bucket LDS ELL
  k_zero_i<<<1, 256, 0, stream>>>(meta, 16);
  k_part2<<<NBLK, 256, 0, stream>>>(ei, pairs, cnt2, ovfAcnt, ovfA);
  k_bucket<<<NB, 256, 0, stream>>>(pairs, cnt2, col, cnt, ovfAcnt, ovfA, ovfBcnt, ovfB);

  // layer 1
  k_gemm<<<NN / 64, 256, 0, stream>>>(x, c1w, nullptr, 0, bufA);
  k_gather_ell<<<NN / 4, 256, 0, stream>>>(bufA, cnt, col, bufB);
  k_ovf<<<32, 64, 0, stream>>>(ovfB, ovfBcnt, cnt, bufA, bufB);

  // layer 2
  k_gemm<<<NN / 64, 256, 0, stream>>>(bufB, c2w, c1b, 1, bufA);
  k_gather_ell<<<NN / 4, 256, 0, stream>>>(bufA, cnt, col, bufB);
  k_ovf<<<32, 64, 0, stream>>>(ovfB, ovfBcnt, cnt, bufA, bufB);

  // blur + head
  k_blur<<<NG * TT * 64 / 256, 256, 0, stream>>>(bufB, c2b, z);
  k_head<<<NG, 64, 0, stream>>>(z, l1w, l1b, l2w, l2b, l3w, l3b, out);
}

// Round 7
// 371.304 us; speedup vs baseline: 2.4423x; 1.0063x over previous
//
#include <hip/hip_runtime.h>
#include <hip/hip_bf16.h>

#define NN 131072      // nodes
#define EE 2097152     // edges
#define NG 256         // graphs
#define TT 8
#define NB 512         // dst buckets (256 nodes each)
#define NBLK 256       // partition blocks (8192 edges each)
#define SCAP 64        // per-(block,bucket) segment capacity
#define MAXW 32        // ELL width (overflow -> exact ovfB list)
#define OVFA_CAP 4096
#define OVFB_CAP 16384

// ---------- zero (int) ----------
__global__ __launch_bounds__(256) void k_zero_i(int* __restrict__ p, int n) {
  int i = blockIdx.x * 256 + threadIdx.x;
  if (i < n) p[i] = 0;
}

// ---------- pass 1: block-private partition, LDS cursors ----------
__global__ __launch_bounds__(256) void k_part2(const int* __restrict__ ei, int* __restrict__ pairs,
                                               int* __restrict__ cnt2, int* __restrict__ ovfAcnt,
                                               int2* __restrict__ ovfA) {
  __shared__ int lcur[NB];
  int tid = threadIdx.x, blk = blockIdx.x;
  lcur[tid] = 0; lcur[tid + 256] = 0;
  __syncthreads();
  int e0 = blk * (EE / NBLK);
#pragma unroll 4
  for (int i = 0; i < (EE / NBLK) / 256; ++i) {
    int e = e0 + i * 256 + tid;
    int s = ei[e], d = ei[EE + e];
    int b = d >> 8;
    int k = atomicAdd(&lcur[b], 1);
    if (k < SCAP)
      __builtin_nontemporal_store(((d & 255) << 17) | s,
                                  &pairs[((size_t)b * NBLK + blk) * SCAP + k]);
    else {
      int oi = atomicAdd(ovfAcnt, 1);
      if (oi < OVFA_CAP) ovfA[oi] = make_int2(d, s);
    }
  }
  __syncthreads();
  cnt2[(size_t)tid * NBLK + blk] = min(lcur[tid], SCAP);
  cnt2[(size_t)(tid + 256) * NBLK + blk] = min(lcur[tid + 256], SCAP);
}

// ---------- pass 2: per-bucket ELL build in LDS ----------
__global__ __launch_bounds__(256) void k_bucket(const int* __restrict__ pairs, const int* __restrict__ cnt2,
                                                int* __restrict__ col, int* __restrict__ cnt,
                                                const int* __restrict__ ovfAcnt, const int2* __restrict__ ovfA,
                                                int* __restrict__ ovfBcnt, int2* __restrict__ ovfB) {
  __shared__ int lcnt[256];
  __shared__ int lell[256 * MAXW];
  __shared__ int scnt[NBLK];
  int b = blockIdx.x, tid = threadIdx.x;
  lcnt[tid] = 0;
  scnt[tid] = cnt2[(size_t)b * NBLK + tid];
  __syncthreads();
  const int* pb = pairs + (size_t)b * NBLK * SCAP;
  for (int idx = tid; idx < NBLK * SCAP; idx += 256) {
    int blk = idx / SCAP, slot = idx % SCAP;
    if (slot < scnt[blk]) {
      int p = pb[idx];
      int s = p & 0x1FFFF, dl = p >> 17;
      int k = atomicAdd(&lcnt[dl], 1);
      if (k < MAXW) lell[dl * MAXW + k] = s;
      else {
        int oi = atomicAdd(ovfBcnt, 1);
        if (oi < OVFB_CAP) ovfB[oi] = make_int2(b * 256 + dl, s);
      }
    }
  }
  int na = min(*ovfAcnt, OVFA_CAP);
  for (int i = tid; i < na; i += 256) {
    int d = ovfA[i].x, s = ovfA[i].y;
    if ((d >> 8) == b) {
      int dl = d & 255;
      int k = atomicAdd(&lcnt[dl], 1);
      if (k < MAXW) lell[dl * MAXW + k] = s;
      else {
        int oi = atomicAdd(ovfBcnt, 1);
        if (oi < OVFB_CAP) ovfB[oi] = make_int2(d, s);
      }
    }
  }
  __syncthreads();
  int4* dst4 = (int4*)(col + (size_t)b * 256 * MAXW);
  const int4* src4 = (const int4*)lell;
#pragma unroll
  for (int i = 0; i < (256 * MAXW / 4) / 256; ++i)
    dst4[tid + i * 256] = src4[tid + i * 256];
  cnt[b * 256 + tid] = lcnt[tid];
}

// ---------- GEMM (layer 1): Y = X @ W ----------
__global__ __launch_bounds__(256) void k_gemm(const float* __restrict__ X, const float* __restrict__ W,
                                              float* __restrict__ Y) {
  __shared__ float xs[64 * 64];
  __shared__ float ws[64 * 64];
  int tid = threadIdx.x;
  size_t row0 = (size_t)blockIdx.x * 64;
#pragma unroll
  for (int i = 0; i < 16; ++i) ws[tid + i * 256] = W[tid + i * 256];
#pragma unroll
  for (int i = 0; i < 4; ++i) {
    int idx = tid + i * 256;
    int r = idx >> 4, q = idx & 15;
    float4 v = ((const float4*)(X + (row0 + r) * 64))[q];
    *(float4*)&xs[idx * 4] = v;
  }
  __syncthreads();
  int c = tid & 63, rg = tid >> 6;
  float acc[16];
#pragma unroll
  for (int i = 0; i < 16; ++i) acc[i] = 0.f;
#pragma unroll 4
  for (int kq = 0; kq < 16; ++kq) {
    float w0 = ws[(kq * 4 + 0) * 64 + c];
    float w1 = ws[(kq * 4 + 1) * 64 + c];
    float w2 = ws[(kq * 4 + 2) * 64 + c];
    float w3 = ws[(kq * 4 + 3) * 64 + c];
#pragma unroll
    for (int i = 0; i < 16; ++i) {
      const float4 xv = *(const float4*)&xs[(rg + i * 4) * 64 + kq * 4];
      acc[i] += xv.x * w0 + xv.y * w1 + xv.z * w2 + xv.w * w3;
    }
  }
#pragma unroll
  for (int i = 0; i < 16; ++i)
    Y[(row0 + rg + (size_t)i * 4) * 64 + c] = acc[i];
}

// ---------- per-wave gather of one node's agg row (returns lane's value) ----------
__device__ __forceinline__ float gather_row(const float* __restrict__ H, const int* __restrict__ cnt,
                                            const int* __restrict__ col, int node, int lane) {
  int deg = cnt[node];
  float dn = rsqrtf((float)deg + 1.0f);
  float acc = H[(size_t)node * 64 + lane] * (dn * dn);   // self loop
  int m = min(deg, MAXW);
  const int* crow = col + (size_t)node * MAXW;
  int myc = (lane < m) ? crow[lane] : 0;
  float mydinv = (lane < m) ? rsqrtf((float)cnt[myc] + 1.0f) : 0.f;
  int j = 0;
  for (; j + 8 <= m; j += 8) {
    int s0 = __shfl(myc, j),     s1 = __shfl(myc, j + 1);
    int s2 = __shfl(myc, j + 2), s3 = __shfl(myc, j + 3);
    int s4 = __shfl(myc, j + 4), s5 = __shfl(myc, j + 5);
    int s6 = __shfl(myc, j + 6), s7 = __shfl(myc, j + 7);
    float c0 = __shfl(mydinv, j),     c1 = __shfl(mydinv, j + 1);
    float c2 = __shfl(mydinv, j + 2), c3 = __shfl(mydinv, j + 3);
    float c4 = __shfl(mydinv, j + 4), c5 = __shfl(mydinv, j + 5);
    float c6 = __shfl(mydinv, j + 6), c7 = __shfl(mydinv, j + 7);
    float h0 = H[(size_t)s0 * 64 + lane];
    float h1 = H[(size_t)s1 * 64 + lane];
    float h2 = H[(size_t)s2 * 64 + lane];
    float h3 = H[(size_t)s3 * 64 + lane];
    float h4 = H[(size_t)s4 * 64 + lane];
    float h5 = H[(size_t)s5 * 64 + lane];
    float h6 = H[(size_t)s6 * 64 + lane];
    float h7 = H[(size_t)s7 * 64 + lane];
    acc += h0 * (c0 * dn) + h1 * (c1 * dn) + h2 * (c2 * dn) + h3 * (c3 * dn)
         + h4 * (c4 * dn) + h5 * (c5 * dn) + h6 * (c6 * dn) + h7 * (c7 * dn);
  }
  for (; j + 4 <= m; j += 4) {
    int s0 = __shfl(myc, j),     s1 = __shfl(myc, j + 1);
    int s2 = __shfl(myc, j + 2), s3 = __shfl(myc, j + 3);
    float c0 = __shfl(mydinv, j),     c1 = __shfl(mydinv, j + 1);
    float c2 = __shfl(mydinv, j + 2), c3 = __shfl(mydinv, j + 3);
    float h0 = H[(size_t)s0 * 64 + lane];
    float h1 = H[(size_t)s1 * 64 + lane];
    float h2 = H[(size_t)s2 * 64 + lane];
    float h3 = H[(size_t)s3 * 64 + lane];
    acc += h0 * (c0 * dn) + h1 * (c1 * dn) + h2 * (c2 * dn) + h3 * (c3 * dn);
  }
  for (; j < m; ++j) {
    int s0 = __shfl(myc, j);
    float c0 = __shfl(mydinv, j);
    acc += H[(size_t)s0 * 64 + lane] * (c0 * dn);
  }
  return acc;
}

// ---------- fused: gather agg1 (64 nodes) -> +ovf -> relu(+b1) -> @W2 -> H2 ----------
__global__ __launch_bounds__(256) void k_gather_gemm(const float* __restrict__ H1, const int* __restrict__ cnt,
                                                     const int* __restrict__ col,
                                                     const int* __restrict__ ovfcnt, const int2* __restrict__ ovf,
                                                     const float* __restrict__ b1v, const float* __restrict__ W2,
                                                     float* __restrict__ H2) {
  __shared__ float xs[64 * 64];
  __shared__ float ws[64 * 64];
  int tid = threadIdx.x;
  int lane = tid & 63, wv = tid >> 6;
  int n0 = blockIdx.x * 64;
#pragma unroll
  for (int i = 0; i < 16; ++i) ws[tid + i * 256] = W2[tid + i * 256];
  // gather phase: 16 nodes per wave
  for (int r = wv * 16; r < wv * 16 + 16; ++r)
    xs[r * 64 + lane] = gather_row(H1, cnt, col, n0 + r, lane);
  __syncthreads();
  // rare ELL-overflow contributions (pre-relu)
  int na = min(*ovfcnt, OVFB_CAP);
  for (int i = wv; i < na; i += 4) {
    int d = ovf[i].x;
    if (d >= n0 && d < n0 + 64) {
      int s = ovf[i].y;
      float v = H1[(size_t)s * 64 + lane] * rsqrtf((float)cnt[s] + 1.0f) * rsqrtf((float)cnt[d] + 1.0f);
      atomicAdd(&xs[(d - n0) * 64 + lane], v);
    }
  }
  __syncthreads();
  // bias + relu in place
#pragma unroll
  for (int i = 0; i < 16; ++i) {
    int idx = tid + i * 256;
    xs[idx] = fmaxf(xs[idx] + b1v[idx & 63], 0.f);
  }
  __syncthreads();
  // GEMM epilogue with W2
  int c = tid & 63, rg = tid >> 6;
  float acc[16];
#pragma unroll
  for (int i = 0; i < 16; ++i) acc[i] = 0.f;
#pragma unroll 4
  for (int kq = 0; kq < 16; ++kq) {
    float w0 = ws[(kq * 4 + 0) * 64 + c];
    float w1 = ws[(kq * 4 + 1) * 64 + c];
    float w2 = ws[(kq * 4 + 2) * 64 + c];
    float w3 = ws[(kq * 4 + 3) * 64 + c];
#pragma unroll
    for (int i = 0; i < 16; ++i) {
      const float4 xv = *(const float4*)&xs[(rg + i * 4) * 64 + kq * 4];
      acc[i] += xv.x * w0 + xv.y * w1 + xv.z * w2 + xv.w * w3;
    }
  }
#pragma unroll
  for (int i = 0; i < 16; ++i)
    H2[((size_t)n0 + rg + (size_t)i * 4) * 64 + c] = acc[i];
}

// ---------- layer-2 gather: one wave per dst node ----------
__global__ __launch_bounds__(256) void k_gather_ell(const float* __restrict__ H, const int* __restrict__ cnt,
                                                    const int* __restrict__ col, float* __restrict__ agg) {
  int lane = threadIdx.x & 63;
  int node = blockIdx.x * 4 + (threadIdx.x >> 6);
  agg[(size_t)node * 64 + lane] = gather_row(H, cnt, col, node, lane);
}

// ---------- exact ELL-overflow fix-up ----------
__global__ __launch_bounds__(64) void k_ovf(const int2* __restrict__ ovf, const int* __restrict__ ovfcnt,
                                            const int* __restrict__ cnt, const float* __restrict__ H,
                                            float* __restrict__ agg) {
  int lane = threadIdx.x;
  int n = min(*ovfcnt, OVFB_CAP);
  for (int i = blockIdx.x; i < n; i += gridDim.x) {
    int d = ovf[i].x, s = ovf[i].y;
    float v = H[(size_t)s * 64 + lane] * rsqrtf((float)cnt[s] + 1.0f) * rsqrtf((float)cnt[d] + 1.0f);
    atomicAdd(&agg[(size_t)d * 64 + lane], v);
  }
}

// ---------- node blur ----------
__global__ __launch_bounds__(256) void k_blur(const float* __restrict__ agg2, const float* __restrict__ b2,
                                              float* __restrict__ z) {
  int idx = blockIdx.x * 256 + threadIdx.x;
  if (idx >= NG * TT * 64) return;
  int f = idx & 63, t = (idx >> 6) & 7, g = idx >> 9;
  const float* base = agg2 + ((size_t)g * 512 + (size_t)t) * 64 + f;
  float acc = 0.f;
#pragma unroll
  for (int rr = 0; rr < 64; ++rr) {
    float w = (float)(63 - rr) * (1.0f / 63.0f);
    acc += w * base[(size_t)rr * 8 * 64];
  }
  z[idx] = acc + 32.0f * b2[f];
}

// ---------- classifier head ----------
__global__ __launch_bounds__(64) void k_head(const float* __restrict__ z,
    const float* __restrict__ w1, const float* __restrict__ b1,
    const float* __restrict__ w2, const float* __restrict__ b2,
    const float* __restrict__ w3, const float* __restrict__ b3,
    float* __restrict__ out) {
  __shared__ float zs[512];
  __shared__ float r[64];
  int g = blockIdx.x, c = threadIdx.x;
#pragma unroll
  for (int i = 0; i < 8; ++i) zs[c + i * 64] = z[(size_t)g * 512 + c + i * 64];
  __syncthreads();
  float a = b1[c];
  for (int j = 0; j < 512; ++j) a += zs[j] * w1[j * 64 + c];
  float mem = 0.f, rate = 0.f;
#pragma unroll
  for (int s = 0; s < 4; ++s) {
    float reset = (mem > 1.0f) ? 1.0f : 0.0f;
    mem = 0.9f * mem + a - reset;
    if (mem - 1.0f > 0.0f) rate += 1.0f;
  }
  r[c] = rate * 0.25f;
  __syncthreads();
  float a2 = b2[c];
#pragma unroll
  for (int j = 0; j < 64; ++j) a2 += r[j] * w2[j * 64 + c];
  __syncthreads();
  mem = 0.f; rate = 0.f;
#pragma unroll
  for (int s = 0; s < 4; ++s) {
    float reset = (mem > 1.0f) ? 1.0f : 0.0f;
    mem = 0.9f * mem + a2 - reset;
    if (mem - 1.0f > 0.0f) rate += 1.0f;
  }
  r[c] = rate * 0.25f;
  __syncthreads();
  if (c < 10) {
    float o = b3[c];
#pragma unroll
    for (int j = 0; j < 64; ++j) o += r[j] * w3[j * 10 + c];
    out[(size_t)g * 10 + c] = o;
  }
}

extern "C" void kernel_launch(void* const* d_in, const int* in_sizes, int n_in,
                              void* d_out, int out_size, void* d_ws, size_t ws_size,
                              hipStream_t stream) {
  const float* x   = (const float*)d_in[0];
  const int*   ei  = (const int*)d_in[1];
  const float* c1w = (const float*)d_in[3];
  const float* c1b = (const float*)d_in[4];
  const float* c2w = (const float*)d_in[5];
  const float* c2b = (const float*)d_in[6];
  const float* l1w = (const float*)d_in[7];
  const float* l1b = (const float*)d_in[8];
  const float* l2w = (const float*)d_in[9];
  const float* l2b = (const float*)d_in[10];
  const float* l3w = (const float*)d_in[11];
  const float* l3b = (const float*)d_in[12];
  float* out = (float*)d_out;

  char* w = (char*)d_ws;
  size_t off = 0;
  float* bufA = (float*)(w + off); off += (size_t)NN * 64 * 4;     // 33.5 MB (pairs overlay)
  float* bufB = (float*)(w + off); off += (size_t)NN * 64 * 4;     // 33.5 MB
  int* col    = (int*)(w + off);   off += (size_t)NN * MAXW * 4;   // 16.8 MB
  int* cnt    = (int*)(w + off);   off += (size_t)NN * 4;
  int* cnt2   = (int*)(w + off);   off += (size_t)NB * NBLK * 4;
  float* z    = (float*)(w + off); off += (size_t)NG * TT * 64 * 4;
  int* meta   = (int*)(w + off);   off += 16 * 4;
  int2* ovfA  = (int2*)(w + off);  off += (size_t)OVFA_CAP * 8;
  int2* ovfB  = (int2*)(w + off);  off += (size_t)OVFB_CAP * 8;
  int* ovfAcnt = meta;
  int* ovfBcnt = meta + 1;
  int* pairs   = (int*)bufA;       // dead before GEMM1 - safe overlay

  // graph build
  k_zero_i<<<1, 256, 0, stream>>>(meta, 16);
  k_part2<<<NBLK, 256, 0, stream>>>(ei, pairs, cnt2, ovfAcnt, ovfA);
  k_bucket<<<NB, 256, 0, stream>>>(pairs, cnt2, col, cnt, ovfAcnt, ovfA, ovfBcnt, ovfB);

  // layer 1 GEMM: H1 = x @ W1  (bufA)
  k_gemm<<<NN / 64, 256, 0, stream>>>(x, c1w, bufA);
  // fused: agg1-gather + ovf + relu(+b1) + @W2 -> H2 (bufB)
  k_gather_gemm<<<NN / 64, 256, 0, stream>>>(bufA, cnt, col, ovfBcnt, ovfB, c1b, c2w, bufB);
  // layer 2 gather: agg2 (bufA)
  k_gather_ell<<<NN / 4, 256, 0, stream>>>(bufB, cnt, col, bufA);
  k_ovf<<<32, 64, 0, stream>>>(ovfB, ovfBcnt, cnt, bufB, bufA);

  // blur + head
  k_blur<<<NG * TT * 64 / 256, 256, 0, stream>>>(bufA, c2b, z);
  k_head<<<NG, 64, 0, stream>>>(z, l1w, l1b, l2w, l2b, l3w, l3b, out);
}

// Round 8
// 327.630 us; speedup vs baseline: 2.7679x; 1.1333x over previous
//
#include <hip/hip_runtime.h>
#include <hip/hip_bf16.h>

#define NN 131072      // nodes
#define EE 2097152     // edges
#define NG 256         // graphs
#define TT 8
#define NB 512         // dst buckets (256 nodes each)
#define NBLK 1024      // partition blocks (2048 edges each, 4 blocks/CU)
#define SCAP 16        // per-(block,bucket) segment capacity (avg 4, P(Po(4)>16)~1e-7)
#define MAXW 32        // ELL width (overflow -> exact ovfB list)
#define OVFA_CAP 4096
#define OVFB_CAP 16384

// ---------- zero (int) ----------
__global__ __launch_bounds__(256) void k_zero_i(int* __restrict__ p, int n) {
  int i = blockIdx.x * 256 + threadIdx.x;
  if (i < n) p[i] = 0;
}

// ---------- pass 1: block-private partition, LDS cursors, block-major layout ----------
__global__ __launch_bounds__(256) void k_part2(const int* __restrict__ ei, int* __restrict__ pairs,
                                               int* __restrict__ cnt2, int* __restrict__ ovfAcnt,
                                               int2* __restrict__ ovfA) {
  __shared__ int lcur[NB];
  int tid = threadIdx.x, blk = blockIdx.x;
  lcur[tid] = 0; lcur[tid + 256] = 0;
  __syncthreads();
  int e0 = blk * (EE / NBLK);
#pragma unroll
  for (int i = 0; i < (EE / NBLK) / 256; ++i) {
    int e = e0 + i * 256 + tid;
    int s = ei[e], d = ei[EE + e];
    int b = d >> 8;
    int k = atomicAdd(&lcur[b], 1);
    if (k < SCAP)
      pairs[((size_t)blk * NB + b) * SCAP + k] = ((d & 255) << 17) | s;
    else {
      int oi = atomicAdd(ovfAcnt, 1);
      if (oi < OVFA_CAP) ovfA[oi] = make_int2(d, s);
    }
  }
  __syncthreads();
  cnt2[(size_t)blk * NB + tid] = min(lcur[tid], SCAP);
  cnt2[(size_t)blk * NB + tid + 256] = min(lcur[tid + 256], SCAP);
}

// ---------- pass 2: per-bucket ELL build in LDS ----------
__global__ __launch_bounds__(256) void k_bucket(const int* __restrict__ pairs, const int* __restrict__ cnt2,
                                                int* __restrict__ col, int* __restrict__ cnt,
                                                const int* __restrict__ ovfAcnt, const int2* __restrict__ ovfA,
                                                int* __restrict__ ovfBcnt, int2* __restrict__ ovfB) {
  __shared__ int lcnt[256];
  __shared__ int lell[256 * MAXW];
  __shared__ int scnt[NBLK];
  int b = blockIdx.x, tid = threadIdx.x;
  lcnt[tid] = 0;
#pragma unroll
  for (int i = 0; i < NBLK / 256; ++i)
    scnt[tid + i * 256] = cnt2[(size_t)(tid + i * 256) * NB + b];
  __syncthreads();
  for (int idx = tid; idx < NBLK * SCAP; idx += 256) {
    int blk = idx >> 4, slot = idx & (SCAP - 1);
    if (slot < scnt[blk]) {
      int p = pairs[(size_t)blk * (NB * SCAP) + b * SCAP + slot];
      int s = p & 0x1FFFF, dl = p >> 17;
      int k = atomicAdd(&lcnt[dl], 1);
      if (k < MAXW) lell[dl * MAXW + k] = s;
      else {
        int oi = atomicAdd(ovfBcnt, 1);
        if (oi < OVFB_CAP) ovfB[oi] = make_int2(b * 256 + dl, s);
      }
    }
  }
  int na = min(*ovfAcnt, OVFA_CAP);
  for (int i = tid; i < na; i += 256) {
    int d = ovfA[i].x, s = ovfA[i].y;
    if ((d >> 8) == b) {
      int dl = d & 255;
      int k = atomicAdd(&lcnt[dl], 1);
      if (k < MAXW) lell[dl * MAXW + k] = s;
      else {
        int oi = atomicAdd(ovfBcnt, 1);
        if (oi < OVFB_CAP) ovfB[oi] = make_int2(d, s);
      }
    }
  }
  __syncthreads();
  int4* dst4 = (int4*)(col + (size_t)b * 256 * MAXW);
  const int4* src4 = (const int4*)lell;
#pragma unroll
  for (int i = 0; i < (256 * MAXW / 4) / 256; ++i)
    dst4[tid + i * 256] = src4[tid + i * 256];
  cnt[b * 256 + tid] = lcnt[tid];
}

// ---------- GEMM: Y[n,c] = sum_k X'[n,k] * W[k,c], X' = relu(X + bias_in) if relu_bias ----------
__global__ __launch_bounds__(256) void k_gemm(const float* __restrict__ X, const float* __restrict__ W,
                                              const float* __restrict__ bias_in, int relu_bias,
                                              float* __restrict__ Y) {
  __shared__ float xs[64 * 64];
  __shared__ float ws[64 * 64];
  int tid = threadIdx.x;
  size_t row0 = (size_t)blockIdx.x * 64;
#pragma unroll
  for (int i = 0; i < 16; ++i) ws[tid + i * 256] = W[tid + i * 256];
#pragma unroll
  for (int i = 0; i < 4; ++i) {
    int idx = tid + i * 256;
    int r = idx >> 4, q = idx & 15;
    float4 v = ((const float4*)(X + (row0 + r) * 64))[q];
    if (relu_bias) {
      int c0 = q * 4;
      v.x = fmaxf(v.x + bias_in[c0 + 0], 0.f);
      v.y = fmaxf(v.y + bias_in[c0 + 1], 0.f);
      v.z = fmaxf(v.z + bias_in[c0 + 2], 0.f);
      v.w = fmaxf(v.w + bias_in[c0 + 3], 0.f);
    }
    *(float4*)&xs[idx * 4] = v;
  }
  __syncthreads();
  int c = tid & 63, rg = tid >> 6;
  float acc[16];
#pragma unroll
  for (int i = 0; i < 16; ++i) acc[i] = 0.f;
#pragma unroll 4
  for (int kq = 0; kq < 16; ++kq) {
    float w0 = ws[(kq * 4 + 0) * 64 + c];
    float w1 = ws[(kq * 4 + 1) * 64 + c];
    float w2 = ws[(kq * 4 + 2) * 64 + c];
    float w3 = ws[(kq * 4 + 3) * 64 + c];
#pragma unroll
    for (int i = 0; i < 16; ++i) {
      const float4 xv = *(const float4*)&xs[(rg + i * 4) * 64 + kq * 4];
      acc[i] += xv.x * w0 + xv.y * w1 + xv.z * w2 + xv.w * w3;
    }
  }
#pragma unroll
  for (int i = 0; i < 16; ++i)
    Y[(row0 + rg + (size_t)i * 4) * 64 + c] = acc[i];
}

// ---------- ELL gather, 2 nodes per wave (ILP): lane = feature ----------
__global__ __launch_bounds__(256) void k_gather_ell(const float* __restrict__ H, const int* __restrict__ cnt,
                                                    const int* __restrict__ col, float* __restrict__ agg) {
  int lane = threadIdx.x & 63;
  int n0 = (blockIdx.x * 4 + (threadIdx.x >> 6)) * 2;
  int n1 = n0 + 1;
  int deg0 = cnt[n0], deg1 = cnt[n1];
  float dn0 = rsqrtf((float)deg0 + 1.0f), dn1 = rsqrtf((float)deg1 + 1.0f);
  float acc0 = H[(size_t)n0 * 64 + lane] * (dn0 * dn0);
  float acc1 = H[(size_t)n1 * 64 + lane] * (dn1 * dn1);
  int m0 = min(deg0, MAXW), m1 = min(deg1, MAXW);
  const int* c0r = col + (size_t)n0 * MAXW;
  const int* c1r = col + (size_t)n1 * MAXW;
  int myc0 = (lane < m0) ? c0r[lane] : 0;
  int myc1 = (lane < m1) ? c1r[lane] : 0;
  float md0 = (lane < m0) ? rsqrtf((float)cnt[myc0] + 1.0f) : 0.f;
  float md1 = (lane < m1) ? rsqrtf((float)cnt[myc1] + 1.0f) : 0.f;
  int mm = max(m0, m1);
  for (int j = 0; j < mm; j += 4) {
    float h[8], cc[8];
#pragma unroll
    for (int k = 0; k < 4; ++k) {
      if (j + k < m0) {          // wave-uniform branch
        int s = __shfl(myc0, j + k);
        cc[k] = __shfl(md0, j + k);
        h[k] = H[(size_t)s * 64 + lane];
      } else { h[k] = 0.f; cc[k] = 0.f; }
      if (j + k < m1) {
        int s = __shfl(myc1, j + k);
        cc[4 + k] = __shfl(md1, j + k);
        h[4 + k] = H[(size_t)s * 64 + lane];
      } else { h[4 + k] = 0.f; cc[4 + k] = 0.f; }
    }
#pragma unroll
    for (int k = 0; k < 4; ++k) {
      acc0 += h[k] * (cc[k] * dn0);
      acc1 += h[4 + k] * (cc[4 + k] * dn1);
    }
  }
  agg[(size_t)n0 * 64 + lane] = acc0;
  agg[(size_t)n1 * 64 + lane] = acc1;
}

// ---------- exact ELL-overflow fix-up ----------
__global__ __launch_bounds__(64) void k_ovf(const int2* __restrict__ ovf, const int* __restrict__ ovfcnt,
                                            const int* __restrict__ cnt, const float* __restrict__ H,
                                            float* __restrict__ agg) {
  int lane = threadIdx.x;
  int n = min(*ovfcnt, OVFB_CAP);
  for (int i = blockIdx.x; i < n; i += gridDim.x) {
    int d = ovf[i].x, s = ovf[i].y;
    float v = H[(size_t)s * 64 + lane] * rsqrtf((float)cnt[s] + 1.0f) * rsqrtf((float)cnt[d] + 1.0f);
    atomicAdd(&agg[(size_t)d * 64 + lane], v);
  }
}

// ---------- node blur ----------
__global__ __launch_bounds__(256) void k_blur(const float* __restrict__ agg2, const float* __restrict__ b2,
                                              float* __restrict__ z) {
  int idx = blockIdx.x * 256 + threadIdx.x;
  if (idx >= NG * TT * 64) return;
  int f = idx & 63, t = (idx >> 6) & 7, g = idx >> 9;
  const float* base = agg2 + ((size_t)g * 512 + (size_t)t) * 64 + f;
  float acc = 0.f;
#pragma unroll
  for (int rr = 0; rr < 64; ++rr) {
    float w = (float)(63 - rr) * (1.0f / 63.0f);
    acc += w * base[(size_t)rr * 8 * 64];
  }
  z[idx] = acc + 32.0f * b2[f];
}

// ---------- classifier head ----------
__global__ __launch_bounds__(64) void k_head(const float* __restrict__ z,
    const float* __restrict__ w1, const float* __restrict__ b1,
    const float* __restrict__ w2, const float* __restrict__ b2,
    const float* __restrict__ w3, const float* __restrict__ b3,
    float* __restrict__ out) {
  __shared__ float zs[512];
  __shared__ float r[64];
  int g = blockIdx.x, c = threadIdx.x;
#pragma unroll
  for (int i = 0; i < 8; ++i) zs[c + i * 64] = z[(size_t)g * 512 + c + i * 64];
  __syncthreads();
  float a = b1[c];
  for (int j = 0; j < 512; ++j) a += zs[j] * w1[j * 64 + c];
  float mem = 0.f, rate = 0.f;
#pragma unroll
  for (int s = 0; s < 4; ++s) {
    float reset = (mem > 1.0f) ? 1.0f : 0.0f;
    mem = 0.9f * mem + a - reset;
    if (mem - 1.0f > 0.0f) rate += 1.0f;
  }
  r[c] = rate * 0.25f;
  __syncthreads();
  float a2 = b2[c];
#pragma unroll
  for (int j = 0; j < 64; ++j) a2 += r[j] * w2[j * 64 + c];
  __syncthreads();
  mem = 0.f; rate = 0.f;
#pragma unroll
  for (int s = 0; s < 4; ++s) {
    float reset = (mem > 1.0f) ? 1.0f : 0.0f;
    mem = 0.9f * mem + a2 - reset;
    if (mem - 1.0f > 0.0f) rate += 1.0f;
  }
  r[c] = rate * 0.25f;
  __syncthreads();
  if (c < 10) {
    float o = b3[c];
#pragma unroll
    for (int j = 0; j < 64; ++j) o += r[j] * w3[j * 10 + c];
    out[(size_t)g * 10 + c] = o;
  }
}

extern "C" void kernel_launch(void* const* d_in, const int* in_sizes, int n_in,
                              void* d_out, int out_size, void* d_ws, size_t ws_size,
                              hipStream_t stream) {
  const float* x   = (const float*)d_in[0];
  const int*   ei  = (const int*)d_in[1];
  const float* c1w = (const float*)d_in[3];
  const float* c1b = (const float*)d_in[4];
  const float* c2w = (const float*)d_in[5];
  const float* c2b = (const float*)d_in[6];
  const float* l1w = (const float*)d_in[7];
  const float* l1b = (const float*)d_in[8];
  const float* l2w = (const float*)d_in[9];
  const float* l2b = (const float*)d_in[10];
  const float* l3w = (const float*)d_in[11];
  const float* l3b = (const float*)d_in[12];
  float* out = (float*)d_out;

  char* w = (char*)d_ws;
  size_t off = 0;
  float* bufA = (float*)(w + off); off += (size_t)NN * 64 * 4;     // 33.5 MB (pairs overlay)
  float* bufB = (float*)(w + off); off += (size_t)NN * 64 * 4;     // 33.5 MB
  int* col    = (int*)(w + off);   off += (size_t)NN * MAXW * 4;   // 16.8 MB
  int* cnt    = (int*)(w + off);   off += (size_t)NN * 4;
  int* cnt2   = (int*)(w + off);   off += (size_t)NBLK * NB * 4;   // 2 MB
  float* z    = (float*)(w + off); off += (size_t)NG * TT * 64 * 4;
  int* meta   = (int*)(w + off);   off += 16 * 4;
  int2* ovfA  = (int2*)(w + off);  off += (size_t)OVFA_CAP * 8;
  int2* ovfB  = (int2*)(w + off);  off += (size_t)OVFB_CAP * 8;
  int* ovfAcnt = meta;
  int* ovfBcnt = meta + 1;
  int* pairs   = (int*)bufA;       // 1024*512*16*4 = 33.5 MB, dead before GEMM1

  // graph build
  k_zero_i<<<1, 256, 0, stream>>>(meta, 16);
  k_part2<<<NBLK, 256, 0, stream>>>(ei, pairs, cnt2, ovfAcnt, ovfA);
  k_bucket<<<NB, 256, 0, stream>>>(pairs, cnt2, col, cnt, ovfAcnt, ovfA, ovfBcnt, ovfB);

  // layer 1: H1 = x @ W1 (bufA); agg1 = gather(H1) (bufB)
  k_gemm<<<NN / 64, 256, 0, stream>>>(x, c1w, nullptr, 0, bufA);
  k_gather_ell<<<NN / 8, 256, 0, stream>>>(bufA, cnt, col, bufB);
  k_ovf<<<32, 64, 0, stream>>>(ovfB, ovfBcnt, cnt, bufA, bufB);

  // layer 2: H2 = relu(agg1+b1) @ W2 (bufA); agg2 = gather(H2) (bufB)
  k_gemm<<<NN / 64, 256, 0, stream>>>(bufB, c2w, c1b, 1, bufA);
  k_gather_ell<<<NN / 8, 256, 0, stream>>>(bufA, cnt, col, bufB);
  k_ovf<<<32, 64, 0, stream>>>(ovfB, ovfBcnt, cnt, bufA, bufB);

  // blur + head
  k_blur<<<NG * TT * 64 / 256, 256, 0, stream>>>(bufB, c2b, z);
  k_head<<<NG, 64, 0, stream>>>(z, l1w, l1b, l2w, l2b, l3w, l3b, out);
}